// Round 7
// baseline (77.136 us; speedup 1.0000x reference)
//
#include <hip/hip_runtime.h>
#include <hip/hip_fp16.h>
#include <math.h>

#define B_ 16
#define C_ 4
#define M_ 2048

typedef short bf16x8 __attribute__((ext_vector_type(8)));
typedef float f32x4 __attribute__((ext_vector_type(4)));

__device__ inline unsigned short f2bf(float f) {
  union { float f; unsigned u; } v; v.f = f;
  unsigned r = v.u + 0x7fffu + ((v.u >> 16) & 1u);
  return (unsigned short)(r >> 16);
}

// Static-index helpers: NO address-taken local arrays.
__device__ inline bf16x8 pack2(float4 a, float4 b) {
  bf16x8 r;
  r[0] = (short)f2bf(a.x); r[1] = (short)f2bf(a.y);
  r[2] = (short)f2bf(a.z); r[3] = (short)f2bf(a.w);
  r[4] = (short)f2bf(b.x); r[5] = (short)f2bf(b.y);
  r[6] = (short)f2bf(b.z); r[7] = (short)f2bf(b.w);
  return r;
}
__device__ inline float4 neg4(float4 a) { return make_float4(-a.x, -a.y, -a.z, -a.w); }
__device__ inline float4 sel4(int c, float4 a, float4 b) {
  return make_float4(c ? a.x : b.x, c ? a.y : b.y, c ? a.z : b.z, c ? a.w : b.w);
}

// Round-6 change: occupancy 2 -> 4 waves/SIMD. The round-4 structure ran 256
// blocks (1/CU) = 2 waves/SIMD; with all spills gone the kernel was still
// ~28 us, i.e. latency-bound with almost no TLP. Halve the m-tile to 64 rows,
// 512 blocks x 512 threads = 2 blocks/CU (LDS 38 KB/block, VGPR set ~115
// unchanged -> 4 waves/SIMD at the allocator's fixed 128-VGPR budget).
// MFMA/twiddle totals unchanged; only the (cheap, L2-resident) B' build is
// duplicated 2x. sincosf -> __sincosf (OCML native; error << bf16 quant).
//   wave = (c, g): bfrag[4][4] = 64 VGPRs (i = g*32 + nt*8 + col/2)
//   per s-step: af[4] + acc[4] + 16 MFMA + in-register Ey epilogue +
//   16-lane butterfly; partials to 4 KB LDS; one barrier; float2 store.
__global__ __launch_bounds__(512) void nufft_kernel(const float* __restrict__ xr,
                                                    const float* __restrict__ xi,
                                                    const float* __restrict__ traj,
                                                    float* __restrict__ out) {
  const int b = blockIdx.x >> 5;
  const int m0 = (blockIdx.x & 31) * 64;
  const int tid = threadIdx.x;
  const int lane = tid & 63;
  const int wave = tid >> 6;
  const int c = wave & 3;
  const int g = wave >> 2;         // i-half this wave owns
  const int col = lane & 15;
  const int quad = lane >> 4;

  __shared__ __align__(16) unsigned short ExS[64][136];  // [m][k] bf16 twiddles
  __shared__ __align__(16) __half2 EyS[64][65];          // [m][i] (re,im) f16
  __shared__ __align__(16) float ypart[2][4][64][2];     // [g][c][m][ro] partials

  // ---- B' fragments for this wave's i-half, built straight from xr/xi.
  // bfrag[nt][ks] = B'[c*128 + (g*4+nt)*16 + col][ks*32 + quad*8 .. +8]
  //   ri = col&1, i = g*32 + nt*8 + col/2; ks0/1: k<64, ks2/3: k>=64.
  bf16x8 bfrag[4][4];
  {
    const int ri = col & 1;
    const float* rb = xr + (size_t)((b * 4 + c) * 64) * 64;
    const float* ib = xi + (size_t)((b * 4 + c) * 64) * 64;
    const int ja = quad * 8;
    const int jb = 32 + quad * 8;
#pragma unroll
    for (int nt = 0; nt < 4; ++nt) {
      const int i = g * 32 + nt * 8 + (col >> 1);
      const float* rrow = rb + i * 64;
      const float* irow = ib + i * 64;
      const float4 r0 = *(const float4*)(rrow + ja);
      const float4 r1 = *(const float4*)(rrow + ja + 4);
      const float4 r2 = *(const float4*)(rrow + jb);
      const float4 r3 = *(const float4*)(rrow + jb + 4);
      const float4 i0 = *(const float4*)(irow + ja);
      const float4 i1 = *(const float4*)(irow + ja + 4);
      const float4 i2 = *(const float4*)(irow + jb);
      const float4 i3 = *(const float4*)(irow + jb + 4);
      // k<64: ri? xi : xr      k>=64: ri? xr : -xi
      bfrag[nt][0] = pack2(sel4(ri, i0, r0), sel4(ri, i1, r1));
      bfrag[nt][1] = pack2(sel4(ri, i2, r2), sel4(ri, i3, r3));
      bfrag[nt][2] = pack2(sel4(ri, r0, neg4(i0)), sel4(ri, r1, neg4(i1)));
      bfrag[nt][3] = pack2(sel4(ri, r2, neg4(i2)), sel4(ri, r3, neg4(i3)));
    }
  }

  // ---- Twiddle generation into LDS (verified recurrence convention).
  // 512 threads, 64 m-rows: 8 threads/row, 8-step segments.
  {
    const int mh = tid >> 3;         // 0..63
    const int j0 = (tid & 7) * 8;    // 8-step segment
    const int mg = m0 + mh;
    const float ky = traj[((size_t)b * M_ + mg) * 2 + 0];
    const float kx = traj[((size_t)b * M_ + mg) * 2 + 1];
    float sa, ca, su, cu;
    // Ex[m][j] = exp(-i*kx*(j-32)); re at k=j, im at k=64+j
    __sincosf(kx * (float)(j0 - 32), &sa, &ca);
    float vr = ca, vi = -sa;
    __sincosf(kx, &su, &cu);
    const float ur = cu, ui = -su;
#pragma unroll
    for (int s = 0; s < 8; ++s) {
      ExS[mh][j0 + s] = f2bf(vr);
      ExS[mh][64 + j0 + s] = f2bf(vi);
      const float nvr = fmaf(vr, ur, -(vi * ui));
      const float nvi = fmaf(vr, ui, vi * ur);
      vr = nvr; vi = nvi;
    }
    // Ey[m][i] = exp(-i*ky*(i-32))
    __sincosf(ky * (float)(j0 - 32), &sa, &ca);
    float wr = ca, wi = -sa;
    __sincosf(ky, &su, &cu);
    const float pr = cu, pi = -su;
#pragma unroll
    for (int s = 0; s < 8; ++s) {
      EyS[mh][j0 + s] = __floats2half2_rn(wr, wi);
      const float nwr = fmaf(wr, pr, -(wi * pi));
      const float nwi = fmaf(wr, pi, wi * pr);
      wr = nwr; wi = nwi;
    }
  }
  __syncthreads();

  const int ri = col & 1;
  const int ih = col >> 1;  // i = g*32 + nt*8 + ih

#pragma unroll 1
  for (int s = 0; s < 4; ++s) {
    // A fragments from LDS (all waves walk the same 4 m-tiles)
    bf16x8 af[4];
#pragma unroll
    for (int ks = 0; ks < 4; ++ks)
      af[ks] = *(const bf16x8*)(&ExS[s * 16 + col][ks * 32 + quad * 8]);

    f32x4 acc[4];
#pragma unroll
    for (int nt = 0; nt < 4; ++nt) acc[nt] = (f32x4){0.f, 0.f, 0.f, 0.f};

#pragma unroll
    for (int ks = 0; ks < 4; ++ks)
#pragma unroll
      for (int nt = 0; nt < 4; ++nt)
        acc[nt] = __builtin_amdgcn_mfma_f32_16x16x32_bf16(af[ks], bfrag[nt][ks], acc[nt], 0, 0, 0);

    // ---- In-register epilogue (this wave's g-half of the i-sum).
    // Lane holds P'[row=quad*4+r][n = c*128 + (g*4+nt)*16 + col].
    //   n even (ri=0): p=Pr[i] -> yr += er*p,  yi += ei*p
    //   n odd  (ri=1): p=Pi[i] -> yr += -ei*p, yi += er*p
    float yr[4], yi[4];
#pragma unroll
    for (int r = 0; r < 4; ++r) {
      const int m_loc = s * 16 + quad * 4 + r;
      float ar = 0.f, ai = 0.f;
#pragma unroll
      for (int nt = 0; nt < 4; ++nt) {
        const __half2 e = EyS[m_loc][g * 32 + nt * 8 + ih];
        const float er = __low2float(e), ei = __high2float(e);
        const float p = acc[nt][r];
        const float ca = ri ? -ei : er;
        const float cb = ri ? er : ei;
        ar = fmaf(ca, p, ar);
        ai = fmaf(cb, p, ai);
      }
      yr[r] = ar; yi[r] = ai;
    }

    // Butterfly reduce over the 16 lanes of this quad-group.
#pragma unroll
    for (int mk = 1; mk <= 8; mk <<= 1) {
#pragma unroll
      for (int r = 0; r < 4; ++r) {
        yr[r] += __shfl_xor(yr[r], mk, 64);
        yi[r] += __shfl_xor(yi[r], mk, 64);
      }
    }

    // Park this wave's partials in LDS (disjoint per (g,c); no barrier needed).
    if (col < 8) {
      const int ro = col & 1;
      const int rr = col >> 1;
      const float v0 = ro ? yi[0] : yr[0];
      const float v1 = ro ? yi[1] : yr[1];
      const float v2 = ro ? yi[2] : yr[2];
      const float v3 = ro ? yi[3] : yr[3];
      const float v = (rr == 0) ? v0 : (rr == 1) ? v1 : (rr == 2) ? v2 : v3;
      ypart[g][c][s * 16 + quad * 4 + rr][ro] = v;
    }
  }

  __syncthreads();

  // Final cross-g reduction + coalesced float2 store. tid<256 -> (c, m_local).
  if (tid < 256) {
    const int cc = tid >> 6;        // 0..3
    const int m = tid & 63;         // 0..63
    const float2 a0 = *(const float2*)&ypart[0][cc][m][0];
    const float2 a1 = *(const float2*)&ypart[1][cc][m][0];
    float2 v;
    v.x = a0.x + a1.x;
    v.y = a0.y + a1.y;
    *(float2*)&out[((size_t)(b * 4 + cc) * M_ + m0 + m) * 2] = v;
  }
}

extern "C" void kernel_launch(void* const* d_in, const int* in_sizes, int n_in,
                              void* d_out, int out_size, void* d_ws, size_t ws_size,
                              hipStream_t stream) {
  const float* xr = (const float*)d_in[0];
  const float* xi = (const float*)d_in[1];
  const float* traj = (const float*)d_in[2];
  float* out = (float*)d_out;
  (void)d_ws; (void)ws_size;  // workspace unused (the 256 MiB poison fill is unconditional anyway)

  nufft_kernel<<<B_ * 32, 512, 0, stream>>>(xr, xi, traj, out);
}

// Round 8
// 68.720 us; speedup vs baseline: 1.1225x; 1.1225x over previous
//
#include <hip/hip_runtime.h>
#include <hip/hip_fp16.h>
#include <math.h>

#define B_ 16
#define C_ 4
#define M_ 2048

typedef short bf16x8 __attribute__((ext_vector_type(8)));
typedef float f32x4 __attribute__((ext_vector_type(4)));

__device__ inline unsigned short f2bf(float f) {
  union { float f; unsigned u; } v; v.f = f;
  unsigned r = v.u + 0x7fffu + ((v.u >> 16) & 1u);
  return (unsigned short)(r >> 16);
}

// Static-index helpers: NO address-taken local arrays.
__device__ inline bf16x8 pack2(float4 a, float4 b) {
  bf16x8 r;
  r[0] = (short)f2bf(a.x); r[1] = (short)f2bf(a.y);
  r[2] = (short)f2bf(a.z); r[3] = (short)f2bf(a.w);
  r[4] = (short)f2bf(b.x); r[5] = (short)f2bf(b.y);
  r[6] = (short)f2bf(b.z); r[7] = (short)f2bf(b.w);
  return r;
}
__device__ inline float4 neg4(float4 a) { return make_float4(-a.x, -a.y, -a.z, -a.w); }
__device__ inline float4 sel4(int c, float4 a, float4 b) {
  return make_float4(c ? a.x : b.x, c ? a.y : b.y, c ? a.z : b.z, c ? a.w : b.w);
}

// Round-8: transposed MFMA + in-register Ey. R6/R7 showed the kernel is
// TLP-invariant at ~30 us (occupancy 2->4 waves/SIMD: no change) -> LDS-pipe
// throughput bound: the old epilogue issued 16 ds_read (EyS) + 32 ds_bpermute
// (4-stage butterfly x 4r x 2) per wave per step. Fix: swap the MFMA operands
// (A<->B; the 16x16x32 operand layouts are symmetric) so D[row=n][col=m].
// The n-reduction is then IN-LANE (4 r x 4 nt values at one m per lane):
//   - butterfly: 2 stages (masks 16,32) x 2 vals = 4 bpermutes/step (was 32)
//   - Ey[m][i] computed in registers per lane (3 __sincosf + rotations);
//     the EyS LDS table, its twiddle-gen half, and its reads are DELETED.
// Geometry unchanged from R4: 256 blocks x 512 thr, wave=(c,g), bfrag[4][4].
__global__ __launch_bounds__(512) void nufft_kernel(const float* __restrict__ xr,
                                                    const float* __restrict__ xi,
                                                    const float* __restrict__ traj,
                                                    float* __restrict__ out) {
  const int b = blockIdx.x >> 4;
  const int m0 = (blockIdx.x & 15) * 128;
  const int tid = threadIdx.x;
  const int lane = tid & 63;
  const int wave = tid >> 6;
  const int c = wave & 3;
  const int g = wave >> 2;         // i-half this wave owns
  const int col = lane & 15;
  const int quad = lane >> 4;

  __shared__ __align__(16) unsigned short ExS[128][136];  // [m][k] bf16 twiddles
  __shared__ __align__(16) float2 ypart[2][4][128];       // [g][c][m] partials

  // ---- B' fragments for this wave's i-half, built straight from xr/xi.
  // bfrag[nt][ks] = B'[c*128 + (g*4+nt)*16 + col][ks*32 + quad*8 .. +8]
  //   ri = col&1, i = g*32 + nt*8 + col/2; ks0/1: k<64, ks2/3: k>=64.
  bf16x8 bfrag[4][4];
  {
    const int ri = col & 1;
    const float* rb = xr + (size_t)((b * 4 + c) * 64) * 64;
    const float* ib = xi + (size_t)((b * 4 + c) * 64) * 64;
    const int ja = quad * 8;
    const int jb = 32 + quad * 8;
#pragma unroll
    for (int nt = 0; nt < 4; ++nt) {
      const int i = g * 32 + nt * 8 + (col >> 1);
      const float* rrow = rb + i * 64;
      const float* irow = ib + i * 64;
      const float4 r0 = *(const float4*)(rrow + ja);
      const float4 r1 = *(const float4*)(rrow + ja + 4);
      const float4 r2 = *(const float4*)(rrow + jb);
      const float4 r3 = *(const float4*)(rrow + jb + 4);
      const float4 i0 = *(const float4*)(irow + ja);
      const float4 i1 = *(const float4*)(irow + ja + 4);
      const float4 i2 = *(const float4*)(irow + jb);
      const float4 i3 = *(const float4*)(irow + jb + 4);
      // k<64: ri? xi : xr      k>=64: ri? xr : -xi
      bfrag[nt][0] = pack2(sel4(ri, i0, r0), sel4(ri, i1, r1));
      bfrag[nt][1] = pack2(sel4(ri, i2, r2), sel4(ri, i3, r3));
      bfrag[nt][2] = pack2(sel4(ri, r0, neg4(i0)), sel4(ri, r1, neg4(i1)));
      bfrag[nt][3] = pack2(sel4(ri, r2, neg4(i2)), sel4(ri, r3, neg4(i3)));
    }
  }

  // ---- Ex twiddle generation into LDS (verified recurrence convention).
  // Ex[m][j] = exp(-i*kx*(j-32)); re at k=j, im at k=64+j. (Ey is in-register now.)
  {
    const int mh = tid >> 2;         // 0..127
    const int j0 = (tid & 3) * 16;   // 16-step segment
    const float kx = traj[((size_t)b * M_ + m0 + mh) * 2 + 1];
    float sa, ca, su, cu;
    __sincosf(kx * (float)(j0 - 32), &sa, &ca);
    float vr = ca, vi = -sa;
    __sincosf(kx, &su, &cu);
    const float ur = cu, ui = -su;
#pragma unroll
    for (int s = 0; s < 16; ++s) {
      ExS[mh][j0 + s] = f2bf(vr);
      ExS[mh][64 + j0 + s] = f2bf(vi);
      const float nvr = fmaf(vr, ur, -(vi * ui));
      const float nvi = fmaf(vr, ui, vi * ur);
      vr = nvr; vi = nvi;
    }
  }
  __syncthreads();

#pragma unroll 1
  for (int s = 0; s < 8; ++s) {
    // ky for this lane's m = m0 + s*16 + col (L1-hot: twiddle phase touched it)
    const float ky = traj[((size_t)b * M_ + m0 + s * 16 + col) * 2 + 0];

    // Ex fragments from LDS (B-operand of the swapped MFMA)
    bf16x8 af[4];
#pragma unroll
    for (int ks = 0; ks < 4; ++ks)
      af[ks] = *(const bf16x8*)(&ExS[s * 16 + col][ks * 32 + quad * 8]);

    f32x4 acc[4];
#pragma unroll
    for (int nt = 0; nt < 4; ++nt) acc[nt] = (f32x4){0.f, 0.f, 0.f, 0.f};

    // SWAPPED operands: D[row = n-within-16][col = m-within-16]
    // acc[nt][r] = P'[n = c*128 + (g*4+nt)*16 + quad*4 + r][m = m0 + s*16 + col]
#pragma unroll
    for (int ks = 0; ks < 4; ++ks)
#pragma unroll
      for (int nt = 0; nt < 4; ++nt)
        acc[nt] = __builtin_amdgcn_mfma_f32_16x16x32_bf16(bfrag[nt][ks], af[ks], acc[nt], 0, 0, 0);

    // ---- In-lane epilogue: y[m] += sum_n Ey-coeff(n) * P'[n][m].
    // n parity: r&1 (Pr at even r, Pi at odd r); i = (g*4+nt)*8 + quad*2 + (r>>1).
    // Ey(i) = exp(-i*ky*(i-32)) = (cos, -sin), computed by rotation chain:
    //   base at i0 = g*32 + quad*2; step +1 via rot1 = (cu,-su); nt-step +8 via rot8.
    float su, cu, s8, c8, sb, cb;
    __sincosf(ky, &su, &cu);
    __sincosf(8.0f * ky, &s8, &c8);
    __sincosf(ky * (float)(g * 32 + quad * 2 - 32), &sb, &cb);
    float er = cb, ei = -sb;
    float yr = 0.f, yi = 0.f;
#pragma unroll
    for (int nt = 0; nt < 4; ++nt) {
      // e1 = e * (cu, -su)
      const float er1 = fmaf(er, cu, ei * su);
      const float ei1 = fmaf(ei, cu, -(er * su));
      yr = fmaf(er, acc[nt][0], fmaf(-ei, acc[nt][1], yr));
      yi = fmaf(ei, acc[nt][0], fmaf(er, acc[nt][1], yi));
      yr = fmaf(er1, acc[nt][2], fmaf(-ei1, acc[nt][3], yr));
      yi = fmaf(ei1, acc[nt][2], fmaf(er1, acc[nt][3], yi));
      // advance base by 8: e *= (c8, -s8)
      const float ern = fmaf(er, c8, ei * s8);
      const float ein = fmaf(ei, c8, -(er * s8));
      er = ern; ei = ein;
    }

    // Reduce over quad (lanes col, col+16, col+32, col+48): 2-stage butterfly.
    yr += __shfl_xor(yr, 16, 64);
    yr += __shfl_xor(yr, 32, 64);
    yi += __shfl_xor(yi, 16, 64);
    yi += __shfl_xor(yi, 32, 64);

    // Park this wave's g-half partial (disjoint per (g,c); no barrier needed).
    if (quad == 0) ypart[g][c][s * 16 + col] = make_float2(yr, yi);
  }

  __syncthreads();

  // Final cross-g reduction + coalesced float2 store. tid -> (c, m_local).
  {
    const int cc = tid >> 7;        // 0..3
    const int m = tid & 127;        // 0..127
    const float2 a0 = ypart[0][cc][m];
    const float2 a1 = ypart[1][cc][m];
    float2 v;
    v.x = a0.x + a1.x;
    v.y = a0.y + a1.y;
    *(float2*)&out[((size_t)(b * 4 + cc) * M_ + m0 + m) * 2] = v;
  }
}

extern "C" void kernel_launch(void* const* d_in, const int* in_sizes, int n_in,
                              void* d_out, int out_size, void* d_ws, size_t ws_size,
                              hipStream_t stream) {
  const float* xr = (const float*)d_in[0];
  const float* xi = (const float*)d_in[1];
  const float* traj = (const float*)d_in[2];
  float* out = (float*)d_out;
  (void)d_ws; (void)ws_size;  // workspace unused (the 256 MiB poison fill is unconditional anyway)

  nufft_kernel<<<B_ * 16, 512, 0, stream>>>(xr, xi, traj, out);
}